// Round 9
// baseline (225.662 us; speedup 1.0000x reference)
//
#include <hip/hip_runtime.h>
#include <math.h>

// LayerNorm_v2: B=8, S=4096, D=1024, f32 in / f32 out.
// Reference quirks replicated:
//  - stats from batch 0 only, broadcast over all batches
//  - "buggy Welford": mean_k=(mean_{k-1}+d_k)/k ; var += (d_k-mean_k)^2 ; var/=(D-1)
//
// v8 = v7b with the streaming pipeline deepened from depth-2 to depth-3:
// batches b+1 AND b+2 are in flight while batch b is stored (8 loads +
// 4 stores outstanding per wave ~= 192 VMEM/CU at 16 waves/CU, vs 64-128
// before — closing the latency*BW product gap: ~140 64B loads/CU needed
// at ~900cy HBM latency). Batch-2 loads are issued before the stats ALU
// so 12 loads are in flight during the stats phase. Everything else is
// the measured-best v4/v7b structure: one wave per row, NT loads+stores,
// per-row scale/bias fold (1 FMA/element), grid 1024x256.
#define BB 8
#define SS 4096
#define DD 1024
#define EPSF 1e-5f

typedef float f32x4 __attribute__((ext_vector_type(4)));

__device__ __forceinline__ f32x4 shfl4(const f32x4 v, int lane) {
    f32x4 r;
    r.x = __shfl(v.x, lane, 64);
    r.y = __shfl(v.y, lane, 64);
    r.z = __shfl(v.z, lane, 64);
    r.w = __shfl(v.w, lane, 64);
    return r;
}
__device__ __forceinline__ f32x4 shfl4_up1(const f32x4 v) {
    f32x4 r;
    r.x = __shfl_up(v.x, 1, 64);
    r.y = __shfl_up(v.y, 1, 64);
    r.z = __shfl_up(v.z, 1, 64);
    r.w = __shfl_up(v.w, 1, 64);
    return r;
}

// Load/store one full batch-row (4 coalesced f32x4 per lane).
#define LOAD_BATCH(dst, b)                                                   \
    _Pragma("unroll")                                                        \
    for (int c = 0; c < 4; ++c)                                              \
        dst[c] = __builtin_nontemporal_load(                                 \
            xp + row4 + (size_t)(b) * batch4 + L + 64 * c);

#define STORE_BATCH(src, b)                                                  \
    _Pragma("unroll")                                                        \
    for (int c = 0; c < 4; ++c) {                                            \
        f32x4 o;                                                             \
        o.x = fmaf(src[c].x, sc[c].x, bs[c].x);                              \
        o.y = fmaf(src[c].y, sc[c].y, bs[c].y);                              \
        o.z = fmaf(src[c].z, sc[c].z, bs[c].z);                              \
        o.w = fmaf(src[c].w, sc[c].w, bs[c].w);                              \
        __builtin_nontemporal_store(                                         \
            o, op + row4 + (size_t)(b) * batch4 + L + 64 * c);               \
    }

__global__ __launch_bounds__(256) void fused_ln_kernel_v8(
    const float* __restrict__ x,
    const float* __restrict__ alpha,
    const float* __restrict__ beta,
    float* __restrict__ out)
{
    const int L   = threadIdx.x & 63;          // lane
    const int wv  = threadIdx.x >> 6;          // wave in block
    const int row = (blockIdx.x << 2) | wv;    // 0..4095, one row per wave
    const size_t row4   = (size_t)row * (DD / 4);
    const size_t batch4 = (size_t)SS * (DD / 4);

    const f32x4* __restrict__ xp = reinterpret_cast<const f32x4*>(x);
    f32x4*       __restrict__ op = reinterpret_cast<f32x4*>(out);

    // ---- batch-0 row (stats input + b0 normalize source)
    f32x4 v[4];
    LOAD_BATCH(v, 0)

    // ---- prefetch batches 1 and 2 + alpha/beta BEFORE the stats ALU:
    // 12 x-loads in flight while the recurrence chains run.
    f32x4 A[4], B[4], T[4];
    LOAD_BATCH(A, 1)
    LOAD_BATCH(B, 2)

    const f32x4* __restrict__ a4 = reinterpret_cast<const f32x4*>(alpha);
    const f32x4* __restrict__ b4 = reinterpret_cast<const f32x4*>(beta);
    f32x4 av[4], bv[4];
#pragma unroll
    for (int c = 0; c < 4; ++c) { av[c] = a4[L + 64 * c]; bv[c] = b4[L + 64 * c]; }

    // ---- stats: 4 chains per lane; chain c covers k in [j0+1, j0+4], j0=256c+4L.
    // Seed mean_{j0} from the 6 preceding elements (closed-form factorial-decay
    // series); window pulled from neighbor lanes via shuffles.
    float var    = 0.0f;
    float m_last = 0.0f;
#pragma unroll
    for (int c = 0; c < 4; ++c) {
        const f32x4 up1 = shfl4_up1(v[c]);                 // lane L-1's chunk c
        const float u2z = __shfl_up(v[c].z, 2, 64);        // lane L-2 .z
        const float u2w = __shfl_up(v[c].w, 2, 64);        // lane L-2 .w
        f32x4 wrap1 = {0.f, 0.f, 0.f, 0.f};
        float wz = 0.f, ww = 0.f;
        if (c > 0) {                                       // compile-time (unrolled)
            wrap1 = shfl4(v[c - 1], 63);                   // elements 256c-4..256c-1
            wz = __shfl(v[c - 1].z, 62, 64);               // element 256c-6
            ww = __shfl(v[c - 1].w, 62, 64);               // element 256c-5
        }

        const float jf = (float)(256 * c + 4 * L);         // j0
        float m;
        if (c == 0 && L == 0) {
            m = 0.0f;                                      // mean_0, exact
        } else if (c == 0 && L == 1) {
            // exact: mean_4 = d4/4 + d3/12 + (d2+d1)/24
            m = up1.w * 0.25f + up1.z * (1.0f / 12.0f)
              + (up1.y + up1.x) * (1.0f / 24.0f);
        } else {
            // window w0..w5 = elements j0-6..j0-1
            const f32x4 w25 = (L == 0) ? wrap1 : up1;      // w2..w5
            float w0, w1;
            if (L >= 2)      { w0 = u2z;     w1 = u2w;     }
            else if (L == 1) { w0 = wrap1.z; w1 = wrap1.w; }
            else             { w0 = wz;      w1 = ww;      }
            float acc = w0;
            acc = fmaf(acc, __builtin_amdgcn_rcpf(jf - 5.0f), w1);
            acc = fmaf(acc, __builtin_amdgcn_rcpf(jf - 4.0f), w25.x);
            acc = fmaf(acc, __builtin_amdgcn_rcpf(jf - 3.0f), w25.y);
            acc = fmaf(acc, __builtin_amdgcn_rcpf(jf - 2.0f), w25.z);
            acc = fmaf(acc, __builtin_amdgcn_rcpf(jf - 1.0f), w25.w);
            m = acc * __builtin_amdgcn_rcpf(jf);
        }

        const float dd[4] = { v[c].x, v[c].y, v[c].z, v[c].w };
#pragma unroll
        for (int t = 0; t < 4; ++t) {
            m = (m + dd[t]) * __builtin_amdgcn_rcpf(jf + (float)(t + 1));
            const float df = dd[t] - m;
            var = fmaf(df, df, var);
        }
        m_last = m;                                        // c=3 end = mean_1024
    }

    // Butterfly: every lane gets the full var; broadcast mean_1024 from lane 63.
#pragma unroll
    for (int off = 32; off >= 1; off >>= 1) var += __shfl_xor(var, off, 64);
    const float mf = __shfl(m_last, 63, 64);
    const float r  = rsqrtf(var * (1.0f / 1023.0f) + EPSF);

    // ---- per-row scale/bias: out = x*sc + bs  (1 FMA per element streaming)
    f32x4 sc[4], bs[4];
#pragma unroll
    for (int c = 0; c < 4; ++c) {
        sc[c].x = av[c].x * r;  sc[c].y = av[c].y * r;
        sc[c].z = av[c].z * r;  sc[c].w = av[c].w * r;
        bs[c].x = fmaf(-mf, sc[c].x, bv[c].x);
        bs[c].y = fmaf(-mf, sc[c].y, bv[c].y);
        bs[c].z = fmaf(-mf, sc[c].z, bv[c].z);
        bs[c].w = fmaf(-mf, sc[c].w, bv[c].w);
    }

    // ---- depth-3 streaming schedule: while storing batch b, loads for
    // b+1 and b+2 are in flight. Buffers rotate A->B->T->A...
    STORE_BATCH(v, 0)          // batch 0 from registers
    LOAD_BATCH(T, 3)           // b3 in flight
    STORE_BATCH(A, 1)
    LOAD_BATCH(A, 4)           // b4 in flight (A's batch-1 data consumed)
    STORE_BATCH(B, 2)
    LOAD_BATCH(B, 5)           // b5 in flight
    STORE_BATCH(T, 3)
    LOAD_BATCH(T, 6)           // b6 in flight
    STORE_BATCH(A, 4)
    LOAD_BATCH(A, 7)           // b7 in flight
    STORE_BATCH(B, 5)
    STORE_BATCH(T, 6)
    STORE_BATCH(A, 7)
}

extern "C" void kernel_launch(void* const* d_in, const int* in_sizes, int n_in,
                              void* d_out, int out_size, void* d_ws, size_t ws_size,
                              hipStream_t stream) {
    (void)in_sizes; (void)n_in; (void)out_size; (void)d_ws; (void)ws_size;
    const float* x     = (const float*)d_in[0];   // (8, 4096, 1024) f32
    const float* alpha = (const float*)d_in[1];   // (1024,) f32
    const float* beta  = (const float*)d_in[2];   // (1024,) f32
    float* out = (float*)d_out;

    hipLaunchKernelGGL(fused_ln_kernel_v8, dim3(SS / 4), dim3(256), 0, stream,
                       x, alpha, beta, out);
}